// Round 13
// baseline (245.782 us; speedup 1.0000x reference)
//
#include <hip/hip_runtime.h>

#define NDIM 32
#define EDIM 16
#define NHID 64
#define NIN1 144
#define SCHUNK 1024  // counts per scan block
#define SPT 4        // counts per thread (256 threads/block)
#define SBLK 128     // streaming blocks appended to hist grid
#define HB 8         // edges per thread in hist (8 atomic RTs in flight)
#define BB 8         // edges per thread in build

// bf16 pack/unpack (RNE). uint holds 2 bf16: lo in [15:0], hi in [31:16].
__device__ __forceinline__ unsigned pk2(float a, float b) {
  unsigned ua = __float_as_uint(a);
  unsigned ub = __float_as_uint(b);
  ua = (ua + 0x7FFFu + ((ua >> 16) & 1u)) >> 16;
  ub = (ub + 0x7FFFu + ((ub >> 16) & 1u)) >> 16;
  return ua | (ub << 16);
}
__device__ __forceinline__ float lo16(unsigned u) { return __uint_as_float(u << 16); }
__device__ __forceinline__ float hi16(unsigned u) { return __uint_as_float(u & 0xFFFF0000u); }

#define ACC8(A, V)                                   \
  do {                                               \
    A[0] += lo16((V).x); A[1] += hi16((V).x);        \
    A[2] += lo16((V).y); A[3] += hi16((V).y);        \
    A[4] += lo16((V).z); A[5] += hi16((V).z);        \
    A[6] += lo16((V).w); A[7] += hi16((V).w);        \
  } while (0)

// ---------------------------------------------------------------------------
// 1) Fused hist + streaming conversions via BLOCK-ROLE split (R12 form).
//    Atomic phase is throughput-capped ~20 G atomics/s (HB 4->8 gave only
//    ~3us) — treated as floor.
// ---------------------------------------------------------------------------
__global__ __launch_bounds__(256) void sse_hist(
    const int* __restrict__ dst, int* __restrict__ counts,
    int* __restrict__ rank,
    const float* __restrict__ W1, float* __restrict__ W1T,
    const float* __restrict__ W2, float* __restrict__ W2T,
    const float* __restrict__ h, uint4* __restrict__ h16,
    int E, int N, int eblocks) {
  int b = blockIdx.x;
  if (b < eblocks) {
    int ebase = b * (256 * HB) + threadIdx.x;
    int r[HB];
#pragma unroll
    for (int i = 0; i < HB; ++i) {
      int e = ebase + i * 256;
      if (e < E) r[i] = atomicAdd(&counts[dst[e]], 1);
    }
#pragma unroll
    for (int i = 0; i < HB; ++i) {
      int e = ebase + i * 256;
      if (e < E) rank[e] = r[i];
    }
  } else {
    int t = (b - eblocks) * 256 + threadIdx.x;
    int T = SBLK * 256;
    if (t < NHID * NIN1) {
      int rr = t / NIN1, k = t - rr * NIN1;
      W1T[k * NHID + rr] = W1[t];
    } else if (t < NHID * NIN1 + NHID * NHID) {
      int i = t - NHID * NIN1;
      int rr = i >> 6, k = i & 63;
      W2T[k * NHID + rr] = W2[i];
    }
    const float4* hf4 = (const float4*)h;
    int NH = N * 8;  // uint4 items; each = 8 bf16 from 2 float4
    for (int i = t; i < NH; i += T) {
      float4 x = hf4[2 * i], y = hf4[2 * i + 1];
      uint4 o;
      o.x = pk2(x.x, x.y); o.y = pk2(x.z, x.w);
      o.z = pk2(y.x, y.y); o.w = pk2(y.z, y.w);
      h16[i] = o;
    }
  }
}

// ---------------------------------------------------------------------------
// 2a) Per-block partial sums (R4 form — never hot).
// ---------------------------------------------------------------------------
__global__ __launch_bounds__(256) void sse_scan_part(
    const int* __restrict__ counts, int* __restrict__ bsum, int N) {
  __shared__ int ws[4];
  int t = threadIdx.x;
  int base = blockIdx.x * SCHUNK + t * SPT;
  int s = 0;
#pragma unroll
  for (int i = 0; i < SPT; ++i) {
    int idx = base + i;
    if (idx < N) s += counts[idx];
  }
  int v = s;
#pragma unroll
  for (int off = 1; off < 64; off <<= 1) v += __shfl_xor(v, off, 64);
  if ((t & 63) == 0) ws[t >> 6] = v;
  __syncthreads();
  if (t == 0) bsum[blockIdx.x] = ws[0] + ws[1] + ws[2] + ws[3];
}

// ---------------------------------------------------------------------------
// 2b) Final scan -> starts. Last block writes starts[N] = E.
// ---------------------------------------------------------------------------
__global__ __launch_bounds__(256) void sse_scan_final(
    const int* __restrict__ counts, const int* __restrict__ bsum,
    int* __restrict__ starts, int N, int nb) {
  __shared__ int ws[4];
  int t = threadIdx.x;
  int lane = t & 63, w = t >> 6;
  int boff = 0;
  for (int j = 0; j < (int)blockIdx.x; ++j) boff += bsum[j];
  int base = blockIdx.x * SCHUNK + t * SPT;
  int c[SPT];
  int s = 0;
#pragma unroll
  for (int i = 0; i < SPT; ++i) {
    int idx = base + i;
    c[i] = (idx < N) ? counts[idx] : 0;
    s += c[i];
  }
  int incl = s;
#pragma unroll
  for (int off = 1; off < 64; off <<= 1) {
    int u = __shfl_up(incl, off, 64);
    if (lane >= off) incl += u;
  }
  if (lane == 63) ws[w] = incl;
  __syncthreads();
  int woff = 0;
#pragma unroll
  for (int j = 0; j < 4; ++j)
    if (j < w) woff += ws[j];
  int run = boff + woff + (incl - s);
#pragma unroll
  for (int i = 0; i < SPT; ++i) {
    int idx = base + i;
    if (idx < N) {
      starts[idx] = run;
      run += c[i];
    }
  }
  if ((int)blockIdx.x == nb - 1 && t == 0)
    starts[N] = boff + ws[0] + ws[1] + ws[2] + ws[3];
}

// ---------------------------------------------------------------------------
// 3) Build: pos = starts[dst] + rank, one int2 store. Now 8 edges/thread
//    (same latency-hiding lever that helped hist: scatter at ILP=8).
// ---------------------------------------------------------------------------
__global__ __launch_bounds__(256) void sse_build(
    const int* __restrict__ src, const int* __restrict__ dst,
    const int* __restrict__ rank, const int* __restrict__ starts,
    int2* __restrict__ sedge, int E) {
  int ebase = blockIdx.x * (256 * BB) + threadIdx.x;
#pragma unroll
  for (int i = 0; i < BB; ++i) {
    int e = ebase + i * 256;
    if (e < E) {
      int d = dst[e];
      int pos = starts[d] + rank[e];
      sedge[pos] = make_int2(src[e], e);
    }
  }
}

// ---------------------------------------------------------------------------
// 4a) Gather pass 0: h16 HALF-ROW 0 (bytes 0..63) + ef-sum.
//     Table-split rationale: full h16 table = 6.4 MB > 4 MiB/XCD L2 ->
//     ~50% miss. Half-row active set = 3.2 MB -> L2-resident -> ~200cyc
//     hits instead of ~900cyc misses. 4 lanes/edge (1 uint4 each),
//     16 edges/instr group; per 32-edge round: 2 h-loads + 2 ef-loads.
//     All shfls uniform flow; accumulates predicated.
// ---------------------------------------------------------------------------
__global__ __launch_bounds__(256) void sse_gather_h0ef(
    const uint4* __restrict__ h16, const float* __restrict__ ef,
    const int2* __restrict__ sedge, const int* __restrict__ starts,
    uint4* __restrict__ efsum16, uint4* __restrict__ hsum16, int N) {
  int w = threadIdx.x >> 6;
  int lane = threadIdx.x & 63;
  int node = blockIdx.x * 4 + w;
  if (node >= N) return;  // wave-uniform
  int st = starts[node], en = starts[node + 1];

  const float4* ef4 = (const float4*)ef;
  int q4 = lane >> 2, m = lane & 3;  // 4 lanes/edge, 16 edges/group

  float acc[8];
#pragma unroll
  for (int i = 0; i < 8; ++i) acc[i] = 0.f;
  float4 ea = make_float4(0.f, 0.f, 0.f, 0.f);

  for (int base = st; base < en; base += 64) {
    int C = en - base; C = C > 64 ? 64 : C;
    int2 seg = (lane < C) ? sedge[base + lane] : make_int2(0, 0);
    int myS = seg.x, myE = seg.y;
    int nr = (C + 31) >> 5;
    for (int r = 0; r < nr; ++r) {
      int b = r * 32;
      int i0 = b + q4, i1 = b + 16 + q4;  // <= 63, uniform flow
      int s0 = __shfl(myS, i0, 64);
      int s1 = __shfl(myS, i1, 64);
      int id0 = __shfl(myE, i0, 64);
      int id1 = __shfl(myE, i1, 64);
      uint4 v0 = h16[(size_t)s0 * 8 + m];        // half 0: uint4 slots 0..3
      uint4 v1 = h16[(size_t)s1 * 8 + m];
      float4 x0 = ef4[(size_t)id0 * 4 + m];
      float4 x1 = ef4[(size_t)id1 * 4 + m];
      if (i0 < C) ACC8(acc, v0);
      if (i1 < C) ACC8(acc, v1);
      if (i0 < C) { ea.x += x0.x; ea.y += x0.y; ea.z += x0.z; ea.w += x0.w; }
      if (i1 < C) { ea.x += x1.x; ea.y += x1.y; ea.z += x1.z; ea.w += x1.w; }
    }
  }

  // h reduce across the 16 edge-groups (lane stride 4), pack bf16
#pragma unroll
  for (int off = 4; off < 64; off <<= 1)
#pragma unroll
    for (int i = 0; i < 8; ++i) acc[i] += __shfl_xor(acc[i], off, 64);
  if (lane < 4) {
    uint4 o;
    o.x = pk2(acc[0], acc[1]); o.y = pk2(acc[2], acc[3]);
    o.z = pk2(acc[4], acc[5]); o.w = pk2(acc[6], acc[7]);
    hsum16[(size_t)node * 8 + lane] = o;  // half 0 slots 0..3
  }
  // ef reduce (lane stride 4), pack pairs of quads (lanes 0..3 hold quads)
#pragma unroll
  for (int off = 4; off < 64; off <<= 1) {
    ea.x += __shfl_xor(ea.x, off, 64);
    ea.y += __shfl_xor(ea.y, off, 64);
    ea.z += __shfl_xor(ea.z, off, 64);
    ea.w += __shfl_xor(ea.w, off, 64);
  }
  float bx = __shfl_xor(ea.x, 1, 64);
  float by = __shfl_xor(ea.y, 1, 64);
  float bz = __shfl_xor(ea.z, 1, 64);
  float bw = __shfl_xor(ea.w, 1, 64);
  if (lane < 4 && (lane & 1) == 0) {
    uint4 o;
    o.x = pk2(ea.x, ea.y); o.y = pk2(ea.z, ea.w);
    o.z = pk2(bx, by);     o.w = pk2(bz, bw);
    efsum16[(size_t)node * 2 + (lane >> 1)] = o;
  }
}

// ---------------------------------------------------------------------------
// 4b) Gather pass 1: h16 HALF-ROW 1 (bytes 64..127). Active table 3.2 MB
//     (L2-resident). Single 64-edge round per chunk: 4 h-loads in flight.
// ---------------------------------------------------------------------------
__global__ __launch_bounds__(256) void sse_gather_h1(
    const uint4* __restrict__ h16, const int2* __restrict__ sedge,
    const int* __restrict__ starts, uint4* __restrict__ hsum16, int N) {
  int w = threadIdx.x >> 6;
  int lane = threadIdx.x & 63;
  int node = blockIdx.x * 4 + w;
  if (node >= N) return;  // wave-uniform
  int st = starts[node], en = starts[node + 1];

  int q4 = lane >> 2, m = lane & 3;  // 4 lanes/edge, 16 edges/group

  float acc[8];
#pragma unroll
  for (int i = 0; i < 8; ++i) acc[i] = 0.f;

  for (int base = st; base < en; base += 64) {
    int C = en - base; C = C > 64 ? 64 : C;
    int2 seg = (lane < C) ? sedge[base + lane] : make_int2(0, 0);
    int myS = seg.x;
    // one 64-edge round: groups at q4, 16+q4, 32+q4, 48+q4 (<=63, uniform)
    int i0 = q4, i1 = 16 + q4, i2 = 32 + q4, i3 = 48 + q4;
    int s0 = __shfl(myS, i0, 64);
    int s1 = __shfl(myS, i1, 64);
    int s2 = __shfl(myS, i2, 64);
    int s3 = __shfl(myS, i3, 64);
    uint4 v0 = h16[(size_t)s0 * 8 + 4 + m];  // half 1: uint4 slots 4..7
    uint4 v1 = h16[(size_t)s1 * 8 + 4 + m];
    uint4 v2 = h16[(size_t)s2 * 8 + 4 + m];
    uint4 v3 = h16[(size_t)s3 * 8 + 4 + m];
    if (i0 < C) ACC8(acc, v0);
    if (i1 < C) ACC8(acc, v1);
    if (i2 < C) ACC8(acc, v2);
    if (i3 < C) ACC8(acc, v3);
  }

#pragma unroll
  for (int off = 4; off < 64; off <<= 1)
#pragma unroll
    for (int i = 0; i < 8; ++i) acc[i] += __shfl_xor(acc[i], off, 64);
  if (lane < 4) {
    uint4 o;
    o.x = pk2(acc[0], acc[1]); o.y = pk2(acc[2], acc[3]);
    o.z = pk2(acc[4], acc[5]); o.w = pk2(acc[6], acc[7]);
    hsum16[(size_t)node * 8 + 4 + lane] = o;  // half 1 slots 4..7
  }
}

// ---------------------------------------------------------------------------
// 5) Node MLP (passed form). Unpacks bf16 mailbox sums into the fp32 LDS
//    z-tile; block = 256 thr = 4 waves = 64 nodes.
// ---------------------------------------------------------------------------
__global__ __launch_bounds__(256) void sse_node(
    const float* __restrict__ h, const float* __restrict__ nf,
    const uint4* __restrict__ efsum16, const uint4* __restrict__ hsum16,
    const int* __restrict__ starts, const float* __restrict__ W1T,
    const float* __restrict__ W2T, float* __restrict__ out, int N) {
  __shared__ float4 zs[36 * 64];  // 36 KB: z (f4 units) [k4][node]
  __shared__ float4 as[16 * 64];  // 16 KB: relu acts [kq][node]

  int tid = threadIdx.x;
  int lane = tid & 63;  // node within block
  int w = __builtin_amdgcn_readfirstlane(tid) >> 6;  // wave id, uniform

  int node = blockIdx.x * 64 + lane;
  int nodeC = node < N ? node : N - 1;

  // ---- stage z: z = [nf(0:8) | dg*nf(8:16) | ef(16:20) | hs(20:36)] f4 ----
  if (w == 0) {
    int st = starts[nodeC], en = starts[nodeC + 1];
    float dg = (float)(en - st);
    const float4* nfr = (const float4*)(nf + (size_t)nodeC * NDIM);
#pragma unroll
    for (int k4 = 0; k4 < 8; ++k4) {
      float4 v = nfr[k4];
      zs[k4 * 64 + lane] = v;
      zs[(8 + k4) * 64 + lane] =
          make_float4(dg * v.x, dg * v.y, dg * v.z, dg * v.w);
    }
  } else if (w == 1) {
    uint4 a = efsum16[(size_t)nodeC * 2 + 0];
    uint4 b = efsum16[(size_t)nodeC * 2 + 1];
    zs[16 * 64 + lane] = make_float4(lo16(a.x), hi16(a.x), lo16(a.y), hi16(a.y));
    zs[17 * 64 + lane] = make_float4(lo16(a.z), hi16(a.z), lo16(a.w), hi16(a.w));
    zs[18 * 64 + lane] = make_float4(lo16(b.x), hi16(b.x), lo16(b.y), hi16(b.y));
    zs[19 * 64 + lane] = make_float4(lo16(b.z), hi16(b.z), lo16(b.w), hi16(b.w));
  } else if (w == 2) {
#pragma unroll
    for (int c = 0; c < 4; ++c) {
      uint4 u = hsum16[(size_t)nodeC * 8 + c];
      zs[(20 + 2 * c) * 64 + lane] =
          make_float4(lo16(u.x), hi16(u.x), lo16(u.y), hi16(u.y));
      zs[(21 + 2 * c) * 64 + lane] =
          make_float4(lo16(u.z), hi16(u.z), lo16(u.w), hi16(u.w));
    }
  } else {
#pragma unroll
    for (int c = 4; c < 8; ++c) {
      uint4 u = hsum16[(size_t)nodeC * 8 + c];
      zs[(20 + 2 * c) * 64 + lane] =
          make_float4(lo16(u.x), hi16(u.x), lo16(u.y), hi16(u.y));
      zs[(21 + 2 * c) * 64 + lane] =
          make_float4(lo16(u.z), hi16(u.z), lo16(u.w), hi16(u.w));
    }
  }
  __syncthreads();

  // ---- layer 1: a[j] = relu(sum_k W1[16w+j][k] z[k]) via W1T[k][r] ----
  const float4* w1b = (const float4*)W1T + w * 4;  // row chunk base (f4)
  float a[16];
#pragma unroll
  for (int j = 0; j < 16; ++j) a[j] = 0.f;

#pragma unroll 2
  for (int k4 = 0; k4 < 36; ++k4) {
    float4 zv = zs[k4 * 64 + lane];
#pragma unroll
    for (int kk = 0; kk < 4; ++kk) {
      int k = k4 * 4 + kk;
      float4 w0 = w1b[k * 16 + 0];
      float4 w1 = w1b[k * 16 + 1];
      float4 w2 = w1b[k * 16 + 2];
      float4 w3 = w1b[k * 16 + 3];
      float zk = kk == 0 ? zv.x : kk == 1 ? zv.y : kk == 2 ? zv.z : zv.w;
      a[0]  = fmaf(w0.x, zk, a[0]);
      a[1]  = fmaf(w0.y, zk, a[1]);
      a[2]  = fmaf(w0.z, zk, a[2]);
      a[3]  = fmaf(w0.w, zk, a[3]);
      a[4]  = fmaf(w1.x, zk, a[4]);
      a[5]  = fmaf(w1.y, zk, a[5]);
      a[6]  = fmaf(w1.z, zk, a[6]);
      a[7]  = fmaf(w1.w, zk, a[7]);
      a[8]  = fmaf(w2.x, zk, a[8]);
      a[9]  = fmaf(w2.y, zk, a[9]);
      a[10] = fmaf(w2.z, zk, a[10]);
      a[11] = fmaf(w2.w, zk, a[11]);
      a[12] = fmaf(w3.x, zk, a[12]);
      a[13] = fmaf(w3.y, zk, a[13]);
      a[14] = fmaf(w3.z, zk, a[14]);
      a[15] = fmaf(w3.w, zk, a[15]);
    }
  }

  // relu + exchange: wave w owns k-range [16w,16w+16) = f4 quads w*4..w*4+3
#pragma unroll
  for (int j4 = 0; j4 < 4; ++j4)
    as[(w * 4 + j4) * 64 + lane] =
        make_float4(fmaxf(a[j4 * 4 + 0], 0.f), fmaxf(a[j4 * 4 + 1], 0.f),
                    fmaxf(a[j4 * 4 + 2], 0.f), fmaxf(a[j4 * 4 + 3], 0.f));
  __syncthreads();

  // ---- layer 2: o[j] = sum_k W2[16w+j][k] act[k] via W2T[k][r] ----
  const float4* w2b = (const float4*)W2T + w * 4;
  float o[16];
#pragma unroll
  for (int j = 0; j < 16; ++j) o[j] = 0.f;

#pragma unroll 2
  for (int kq = 0; kq < 16; ++kq) {
    float4 av = as[kq * 64 + lane];
#pragma unroll
    for (int kk = 0; kk < 4; ++kk) {
      int k = kq * 4 + kk;
      float4 w0 = w2b[k * 16 + 0];
      float4 w1 = w2b[k * 16 + 1];
      float4 w2 = w2b[k * 16 + 2];
      float4 w3 = w2b[k * 16 + 3];
      float ak = kk == 0 ? av.x : kk == 1 ? av.y : kk == 2 ? av.z : av.w;
      o[0]  = fmaf(w0.x, ak, o[0]);
      o[1]  = fmaf(w0.y, ak, o[1]);
      o[2]  = fmaf(w0.z, ak, o[2]);
      o[3]  = fmaf(w0.w, ak, o[3]);
      o[4]  = fmaf(w1.x, ak, o[4]);
      o[5]  = fmaf(w1.y, ak, o[5]);
      o[6]  = fmaf(w1.z, ak, o[6]);
      o[7]  = fmaf(w1.w, ak, o[7]);
      o[8]  = fmaf(w2.x, ak, o[8]);
      o[9]  = fmaf(w2.y, ak, o[9]);
      o[10] = fmaf(w2.z, ak, o[10]);
      o[11] = fmaf(w2.w, ak, o[11]);
      o[12] = fmaf(w3.x, ak, o[12]);
      o[13] = fmaf(w3.y, ak, o[13]);
      o[14] = fmaf(w3.z, ak, o[14]);
      o[15] = fmaf(w3.w, ak, o[15]);
    }
  }

  // ---- store rows [16w,16w+16) of node; deg==0 passthrough (rare) ----
  if (node < N) {
    int st = starts[node], en = starts[node + 1];
    float4* o4 = (float4*)(out + (size_t)node * NHID + w * 16);
    if (en - st == 0) {
      const float4* hr = (const float4*)(h + (size_t)node * NHID + w * 16);
#pragma unroll
      for (int j4 = 0; j4 < 4; ++j4) o4[j4] = hr[j4];
    } else {
#pragma unroll
      for (int j4 = 0; j4 < 4; ++j4)
        o4[j4] = make_float4(o[j4 * 4 + 0], o[j4 * 4 + 1], o[j4 * 4 + 2],
                             o[j4 * 4 + 3]);
    }
  }
}

extern "C" void kernel_launch(void* const* d_in, const int* in_sizes, int n_in,
                              void* d_out, int out_size, void* d_ws, size_t ws_size,
                              hipStream_t stream) {
  const float* h  = (const float*)d_in[0];
  const float* nf = (const float*)d_in[1];
  const float* ef = (const float*)d_in[2];
  const int*   src = (const int*)d_in[3];
  const int*   dst = (const int*)d_in[4];
  const float* W1 = (const float*)d_in[5];
  const float* W2 = (const float*)d_in[6];
  float* out = (float*)d_out;

  int N = in_sizes[0] / NHID;  // h is [N, 64]
  int E = in_sizes[3];         // src is [E]

  // ws layout (bytes), total ~21.5 MB:
  // sedge[E] int2 | counts[N] | starts[N+1] | bsum[64] | W1T | W2T |
  // pad16 | h16[N*128B] | efsum16[N*32B] | hsum16[N*128B]
  // rank[E] ALIASES hsum16 (hist writes rank; build reads it; gather then
  // overwrites hsum16 — stream-ordered).
  char* p = (char*)d_ws;
  int2* sedge = (int2*)p;                 p += (size_t)E * 8;
  int* counts = (int*)p;                  p += (size_t)N * 4;
  int* starts = (int*)p;                  p += (size_t)(N + 1) * 4;
  int* bsum = (int*)p;                    p += 64 * 4;
  float* W1T = (float*)p;                 p += (size_t)NIN1 * NHID * 4;
  float* W2T = (float*)p;                 p += (size_t)NHID * NHID * 4;
  p = (char*)(((size_t)p + 15) & ~(size_t)15);
  uint4* h16 = (uint4*)p;                 p += (size_t)N * 128;
  uint4* efsum16 = (uint4*)p;             p += (size_t)N * 32;
  uint4* hsum16 = (uint4*)p;              p += (size_t)N * 128;
  int* rank = (int*)hsum16;               // E*4 = 3.2 MB <= N*128 = 6.4 MB

  hipMemsetAsync(counts, 0, (size_t)N * sizeof(int), stream);

  int eblocks8 = (E + 256 * HB - 1) / (256 * HB);  // 391 edge-blocks
  int bblocks  = (E + 256 * BB - 1) / (256 * BB);  // 391 build blocks
  int nb = (N + SCHUNK - 1) / SCHUNK;              // 49 for N=50000

  sse_hist<<<eblocks8 + SBLK, 256, 0, stream>>>(dst, counts, rank, W1, W1T,
                                                W2, W2T, h, h16, E, N,
                                                eblocks8);
  sse_scan_part<<<nb, 256, 0, stream>>>(counts, bsum, N);
  sse_scan_final<<<nb, 256, 0, stream>>>(counts, bsum, starts, N, nb);
  sse_build<<<bblocks, 256, 0, stream>>>(src, dst, rank, starts, sedge, E);

  int gblocks = (N + 3) / 4;  // 1 node/wave, 4 per block
  sse_gather_h0ef<<<gblocks, 256, 0, stream>>>(h16, ef, sedge, starts,
                                               efsum16, hsum16, N);
  sse_gather_h1<<<gblocks, 256, 0, stream>>>(h16, sedge, starts, hsum16, N);

  int nblocks = (N + 63) / 64;  // 782 blocks x 4 waves = 3128 waves
  sse_node<<<nblocks, 256, 0, stream>>>(h, nf, efsum16, hsum16, starts, W1T,
                                        W2T, out, N);
}

// Round 14
// 225.456 us; speedup vs baseline: 1.0902x; 1.0902x over previous
//
#include <hip/hip_runtime.h>

#define NDIM 32
#define EDIM 16
#define NHID 64
#define NIN1 144
#define SCHUNK 1024  // counts per scan block
#define SPT 4        // counts per thread (256 threads/block)
#define SBLK 128     // streaming blocks appended to hist grid
#define HB 8         // edges per thread in hist (8 atomic RTs in flight)
#define BB 8         // edges per thread in build

// bf16 pack/unpack (RNE). uint holds 2 bf16: lo in [15:0], hi in [31:16].
__device__ __forceinline__ unsigned pk2(float a, float b) {
  unsigned ua = __float_as_uint(a);
  unsigned ub = __float_as_uint(b);
  ua = (ua + 0x7FFFu + ((ua >> 16) & 1u)) >> 16;
  ub = (ub + 0x7FFFu + ((ub >> 16) & 1u)) >> 16;
  return ua | (ub << 16);
}
__device__ __forceinline__ float lo16(unsigned u) { return __uint_as_float(u << 16); }
__device__ __forceinline__ float hi16(unsigned u) { return __uint_as_float(u & 0xFFFF0000u); }

#define ACC8(A, V)                                   \
  do {                                               \
    A[0] += lo16((V).x); A[1] += hi16((V).x);        \
    A[2] += lo16((V).y); A[3] += hi16((V).y);        \
    A[4] += lo16((V).z); A[5] += hi16((V).z);        \
    A[6] += lo16((V).w); A[7] += hi16((V).w);        \
  } while (0)

// ---------------------------------------------------------------------------
// 1) Fused hist + streaming conversions via BLOCK-ROLE split (R12 form).
//    Atomic phase is throughput-capped ~20 G atomics/s (flat HB 4->8) —
//    treated as the algorithmic floor for the rank scheme.
// ---------------------------------------------------------------------------
__global__ __launch_bounds__(256) void sse_hist(
    const int* __restrict__ dst, int* __restrict__ counts,
    int* __restrict__ rank,
    const float* __restrict__ W1, float* __restrict__ W1T,
    const float* __restrict__ W2, float* __restrict__ W2T,
    const float* __restrict__ h, uint4* __restrict__ h16,
    int E, int N, int eblocks) {
  int b = blockIdx.x;
  if (b < eblocks) {
    int ebase = b * (256 * HB) + threadIdx.x;
    int r[HB];
#pragma unroll
    for (int i = 0; i < HB; ++i) {
      int e = ebase + i * 256;
      if (e < E) r[i] = atomicAdd(&counts[dst[e]], 1);
    }
#pragma unroll
    for (int i = 0; i < HB; ++i) {
      int e = ebase + i * 256;
      if (e < E) rank[e] = r[i];
    }
  } else {
    int t = (b - eblocks) * 256 + threadIdx.x;
    int T = SBLK * 256;
    if (t < NHID * NIN1) {
      int rr = t / NIN1, k = t - rr * NIN1;
      W1T[k * NHID + rr] = W1[t];
    } else if (t < NHID * NIN1 + NHID * NHID) {
      int i = t - NHID * NIN1;
      int rr = i >> 6, k = i & 63;
      W2T[k * NHID + rr] = W2[i];
    }
    const float4* hf4 = (const float4*)h;
    int NH = N * 8;  // uint4 items; each = 8 bf16 from 2 float4
    for (int i = t; i < NH; i += T) {
      float4 x = hf4[2 * i], y = hf4[2 * i + 1];
      uint4 o;
      o.x = pk2(x.x, x.y); o.y = pk2(x.z, x.w);
      o.z = pk2(y.x, y.y); o.w = pk2(y.z, y.w);
      h16[i] = o;
    }
  }
}

// ---------------------------------------------------------------------------
// 2a) Per-block partial sums (R4 form — never hot).
// ---------------------------------------------------------------------------
__global__ __launch_bounds__(256) void sse_scan_part(
    const int* __restrict__ counts, int* __restrict__ bsum, int N) {
  __shared__ int ws[4];
  int t = threadIdx.x;
  int base = blockIdx.x * SCHUNK + t * SPT;
  int s = 0;
#pragma unroll
  for (int i = 0; i < SPT; ++i) {
    int idx = base + i;
    if (idx < N) s += counts[idx];
  }
  int v = s;
#pragma unroll
  for (int off = 1; off < 64; off <<= 1) v += __shfl_xor(v, off, 64);
  if ((t & 63) == 0) ws[t >> 6] = v;
  __syncthreads();
  if (t == 0) bsum[blockIdx.x] = ws[0] + ws[1] + ws[2] + ws[3];
}

// ---------------------------------------------------------------------------
// 2b) Final scan -> starts. Last block writes starts[N] = E.
// ---------------------------------------------------------------------------
__global__ __launch_bounds__(256) void sse_scan_final(
    const int* __restrict__ counts, const int* __restrict__ bsum,
    int* __restrict__ starts, int N, int nb) {
  __shared__ int ws[4];
  int t = threadIdx.x;
  int lane = t & 63, w = t >> 6;
  int boff = 0;
  for (int j = 0; j < (int)blockIdx.x; ++j) boff += bsum[j];
  int base = blockIdx.x * SCHUNK + t * SPT;
  int c[SPT];
  int s = 0;
#pragma unroll
  for (int i = 0; i < SPT; ++i) {
    int idx = base + i;
    c[i] = (idx < N) ? counts[idx] : 0;
    s += c[i];
  }
  int incl = s;
#pragma unroll
  for (int off = 1; off < 64; off <<= 1) {
    int u = __shfl_up(incl, off, 64);
    if (lane >= off) incl += u;
  }
  if (lane == 63) ws[w] = incl;
  __syncthreads();
  int woff = 0;
#pragma unroll
  for (int j = 0; j < 4; ++j)
    if (j < w) woff += ws[j];
  int run = boff + woff + (incl - s);
#pragma unroll
  for (int i = 0; i < SPT; ++i) {
    int idx = base + i;
    if (idx < N) {
      starts[idx] = run;
      run += c[i];
    }
  }
  if ((int)blockIdx.x == nb - 1 && t == 0)
    starts[N] = boff + ws[0] + ws[1] + ws[2] + ws[3];
}

// ---------------------------------------------------------------------------
// 3) Build: pos = starts[dst] + rank, one int2 store. 8 edges/thread
//    (latency-bound scatter at ILP=8; left top-5 in R13).
// ---------------------------------------------------------------------------
__global__ __launch_bounds__(256) void sse_build(
    const int* __restrict__ src, const int* __restrict__ dst,
    const int* __restrict__ rank, const int* __restrict__ starts,
    int2* __restrict__ sedge, int E) {
  int ebase = blockIdx.x * (256 * BB) + threadIdx.x;
#pragma unroll
  for (int i = 0; i < BB; ++i) {
    int e = ebase + i * 256;
    if (e < E) {
      int d = dst[e];
      int pos = starts[d] + rank[e];
      sedge[pos] = make_int2(src[e], e);
    }
  }
}

// ---------------------------------------------------------------------------
// 4) Gather — R12-EXACT single-pass form (proven ~40.9us x3; the R13
//    two-pass table-split REFUTED: combined ~60us — pass0 halved MLP and
//    duplicated the sedge walk). MLP x TLP balance: 32-edge rounds,
//    6 loads in flight, VGPR 32, occ ~68%. bf16 h + fp32 ef, 1 node/wave.
//    All shfls in uniform flow; accumulates predicated.
// ---------------------------------------------------------------------------
__global__ __launch_bounds__(256) void sse_gather(
    const uint4* __restrict__ h16, const float* __restrict__ ef,
    const int2* __restrict__ sedge, const int* __restrict__ starts,
    uint4* __restrict__ efsum16, uint4* __restrict__ hsum16, int N) {
  int w = threadIdx.x >> 6;
  int lane = threadIdx.x & 63;
  int node = blockIdx.x * 4 + w;
  if (node >= N) return;  // wave-uniform
  int st = starts[node], en = starts[node + 1];

  const float4* ef4 = (const float4*)ef;
  int q8 = lane >> 3, m = lane & 7;   // h: 8 lanes/edge, 8 edges/instr
  int eq = lane >> 2, em = lane & 3;  // ef: 4 lanes/edge, 16 edges/instr

  float acc[8];
#pragma unroll
  for (int i = 0; i < 8; ++i) acc[i] = 0.f;
  float4 ea = make_float4(0.f, 0.f, 0.f, 0.f);

  for (int base = st; base < en; base += 64) {
    int C = en - base; C = C > 64 ? 64 : C;
    int2 seg = (lane < C) ? sedge[base + lane] : make_int2(0, 0);
    int myS = seg.x, myE = seg.y;
    int nr = (C + 31) >> 5;
    for (int r = 0; r < nr; ++r) {
      int b = r * 32;
      int i0 = b + q8, i1 = b + 8 + q8, i2 = b + 16 + q8, i3 = b + 24 + q8;
      int s0 = __shfl(myS, i0, 64);
      int s1 = __shfl(myS, i1, 64);
      int s2 = __shfl(myS, i2, 64);
      int s3 = __shfl(myS, i3, 64);
      int e0 = b + eq, e1 = b + 16 + eq;
      int id0 = __shfl(myE, e0, 64);
      int id1 = __shfl(myE, e1, 64);
      uint4 v0 = h16[(size_t)s0 * 8 + m];
      uint4 v1 = h16[(size_t)s1 * 8 + m];
      uint4 v2 = h16[(size_t)s2 * 8 + m];
      uint4 v3 = h16[(size_t)s3 * 8 + m];
      float4 x0 = ef4[(size_t)id0 * 4 + em];
      float4 x1 = ef4[(size_t)id1 * 4 + em];
      if (i0 < C) ACC8(acc, v0);
      if (i1 < C) ACC8(acc, v1);
      if (i2 < C) ACC8(acc, v2);
      if (i3 < C) ACC8(acc, v3);
      if (e0 < C) { ea.x += x0.x; ea.y += x0.y; ea.z += x0.z; ea.w += x0.w; }
      if (e1 < C) { ea.x += x1.x; ea.y += x1.y; ea.z += x1.z; ea.w += x1.w; }
    }
  }

  // h reduce across the 8 edge-subgroups (stride 8 lanes), pack bf16
#pragma unroll
  for (int off = 8; off < 64; off <<= 1)
#pragma unroll
    for (int i = 0; i < 8; ++i) acc[i] += __shfl_xor(acc[i], off, 64);
  if (lane < 8) {
    uint4 o;
    o.x = pk2(acc[0], acc[1]); o.y = pk2(acc[2], acc[3]);
    o.z = pk2(acc[4], acc[5]); o.w = pk2(acc[6], acc[7]);
    hsum16[(size_t)node * 8 + lane] = o;
  }
  // ef reduce across 16 edge-groups (stride 4 lanes), pack pairs of quads
#pragma unroll
  for (int off = 4; off < 64; off <<= 1) {
    ea.x += __shfl_xor(ea.x, off, 64);
    ea.y += __shfl_xor(ea.y, off, 64);
    ea.z += __shfl_xor(ea.z, off, 64);
    ea.w += __shfl_xor(ea.w, off, 64);
  }
  float bx = __shfl_xor(ea.x, 1, 64);
  float by = __shfl_xor(ea.y, 1, 64);
  float bz = __shfl_xor(ea.z, 1, 64);
  float bw = __shfl_xor(ea.w, 1, 64);
  if (lane < 4 && (lane & 1) == 0) {
    uint4 o;
    o.x = pk2(ea.x, ea.y); o.y = pk2(ea.z, ea.w);
    o.z = pk2(bx, by);     o.w = pk2(bz, bw);
    efsum16[(size_t)node * 2 + (lane >> 1)] = o;
  }
}

// ---------------------------------------------------------------------------
// 5) Node MLP (passed form). Unpacks bf16 mailbox sums into the fp32 LDS
//    z-tile; block = 256 thr = 4 waves = 64 nodes.
// ---------------------------------------------------------------------------
__global__ __launch_bounds__(256) void sse_node(
    const float* __restrict__ h, const float* __restrict__ nf,
    const uint4* __restrict__ efsum16, const uint4* __restrict__ hsum16,
    const int* __restrict__ starts, const float* __restrict__ W1T,
    const float* __restrict__ W2T, float* __restrict__ out, int N) {
  __shared__ float4 zs[36 * 64];  // 36 KB: z (f4 units) [k4][node]
  __shared__ float4 as[16 * 64];  // 16 KB: relu acts [kq][node]

  int tid = threadIdx.x;
  int lane = tid & 63;  // node within block
  int w = __builtin_amdgcn_readfirstlane(tid) >> 6;  // wave id, uniform

  int node = blockIdx.x * 64 + lane;
  int nodeC = node < N ? node : N - 1;

  // ---- stage z: z = [nf(0:8) | dg*nf(8:16) | ef(16:20) | hs(20:36)] f4 ----
  if (w == 0) {
    int st = starts[nodeC], en = starts[nodeC + 1];
    float dg = (float)(en - st);
    const float4* nfr = (const float4*)(nf + (size_t)nodeC * NDIM);
#pragma unroll
    for (int k4 = 0; k4 < 8; ++k4) {
      float4 v = nfr[k4];
      zs[k4 * 64 + lane] = v;
      zs[(8 + k4) * 64 + lane] =
          make_float4(dg * v.x, dg * v.y, dg * v.z, dg * v.w);
    }
  } else if (w == 1) {
    uint4 a = efsum16[(size_t)nodeC * 2 + 0];
    uint4 b = efsum16[(size_t)nodeC * 2 + 1];
    zs[16 * 64 + lane] = make_float4(lo16(a.x), hi16(a.x), lo16(a.y), hi16(a.y));
    zs[17 * 64 + lane] = make_float4(lo16(a.z), hi16(a.z), lo16(a.w), hi16(a.w));
    zs[18 * 64 + lane] = make_float4(lo16(b.x), hi16(b.x), lo16(b.y), hi16(b.y));
    zs[19 * 64 + lane] = make_float4(lo16(b.z), hi16(b.z), lo16(b.w), hi16(b.w));
  } else if (w == 2) {
#pragma unroll
    for (int c = 0; c < 4; ++c) {
      uint4 u = hsum16[(size_t)nodeC * 8 + c];
      zs[(20 + 2 * c) * 64 + lane] =
          make_float4(lo16(u.x), hi16(u.x), lo16(u.y), hi16(u.y));
      zs[(21 + 2 * c) * 64 + lane] =
          make_float4(lo16(u.z), hi16(u.z), lo16(u.w), hi16(u.w));
    }
  } else {
#pragma unroll
    for (int c = 4; c < 8; ++c) {
      uint4 u = hsum16[(size_t)nodeC * 8 + c];
      zs[(20 + 2 * c) * 64 + lane] =
          make_float4(lo16(u.x), hi16(u.x), lo16(u.y), hi16(u.y));
      zs[(21 + 2 * c) * 64 + lane] =
          make_float4(lo16(u.z), hi16(u.z), lo16(u.w), hi16(u.w));
    }
  }
  __syncthreads();

  // ---- layer 1: a[j] = relu(sum_k W1[16w+j][k] z[k]) via W1T[k][r] ----
  const float4* w1b = (const float4*)W1T + w * 4;  // row chunk base (f4)
  float a[16];
#pragma unroll
  for (int j = 0; j < 16; ++j) a[j] = 0.f;

#pragma unroll 2
  for (int k4 = 0; k4 < 36; ++k4) {
    float4 zv = zs[k4 * 64 + lane];
#pragma unroll
    for (int kk = 0; kk < 4; ++kk) {
      int k = k4 * 4 + kk;
      float4 w0 = w1b[k * 16 + 0];
      float4 w1 = w1b[k * 16 + 1];
      float4 w2 = w1b[k * 16 + 2];
      float4 w3 = w1b[k * 16 + 3];
      float zk = kk == 0 ? zv.x : kk == 1 ? zv.y : kk == 2 ? zv.z : zv.w;
      a[0]  = fmaf(w0.x, zk, a[0]);
      a[1]  = fmaf(w0.y, zk, a[1]);
      a[2]  = fmaf(w0.z, zk, a[2]);
      a[3]  = fmaf(w0.w, zk, a[3]);
      a[4]  = fmaf(w1.x, zk, a[4]);
      a[5]  = fmaf(w1.y, zk, a[5]);
      a[6]  = fmaf(w1.z, zk, a[6]);
      a[7]  = fmaf(w1.w, zk, a[7]);
      a[8]  = fmaf(w2.x, zk, a[8]);
      a[9]  = fmaf(w2.y, zk, a[9]);
      a[10] = fmaf(w2.z, zk, a[10]);
      a[11] = fmaf(w2.w, zk, a[11]);
      a[12] = fmaf(w3.x, zk, a[12]);
      a[13] = fmaf(w3.y, zk, a[13]);
      a[14] = fmaf(w3.z, zk, a[14]);
      a[15] = fmaf(w3.w, zk, a[15]);
    }
  }

  // relu + exchange: wave w owns k-range [16w,16w+16) = f4 quads w*4..w*4+3
#pragma unroll
  for (int j4 = 0; j4 < 4; ++j4)
    as[(w * 4 + j4) * 64 + lane] =
        make_float4(fmaxf(a[j4 * 4 + 0], 0.f), fmaxf(a[j4 * 4 + 1], 0.f),
                    fmaxf(a[j4 * 4 + 2], 0.f), fmaxf(a[j4 * 4 + 3], 0.f));
  __syncthreads();

  // ---- layer 2: o[j] = sum_k W2[16w+j][k] act[k] via W2T[k][r] ----
  const float4* w2b = (const float4*)W2T + w * 4;
  float o[16];
#pragma unroll
  for (int j = 0; j < 16; ++j) o[j] = 0.f;

#pragma unroll 2
  for (int kq = 0; kq < 16; ++kq) {
    float4 av = as[kq * 64 + lane];
#pragma unroll
    for (int kk = 0; kk < 4; ++kk) {
      int k = kq * 4 + kk;
      float4 w0 = w2b[k * 16 + 0];
      float4 w1 = w2b[k * 16 + 1];
      float4 w2 = w2b[k * 16 + 2];
      float4 w3 = w2b[k * 16 + 3];
      float ak = kk == 0 ? av.x : kk == 1 ? av.y : kk == 2 ? av.z : av.w;
      o[0]  = fmaf(w0.x, ak, o[0]);
      o[1]  = fmaf(w0.y, ak, o[1]);
      o[2]  = fmaf(w0.z, ak, o[2]);
      o[3]  = fmaf(w0.w, ak, o[3]);
      o[4]  = fmaf(w1.x, ak, o[4]);
      o[5]  = fmaf(w1.y, ak, o[5]);
      o[6]  = fmaf(w1.z, ak, o[6]);
      o[7]  = fmaf(w1.w, ak, o[7]);
      o[8]  = fmaf(w2.x, ak, o[8]);
      o[9]  = fmaf(w2.y, ak, o[9]);
      o[10] = fmaf(w2.z, ak, o[10]);
      o[11] = fmaf(w2.w, ak, o[11]);
      o[12] = fmaf(w3.x, ak, o[12]);
      o[13] = fmaf(w3.y, ak, o[13]);
      o[14] = fmaf(w3.z, ak, o[14]);
      o[15] = fmaf(w3.w, ak, o[15]);
    }
  }

  // ---- store rows [16w,16w+16) of node; deg==0 passthrough (rare) ----
  if (node < N) {
    int st = starts[node], en = starts[node + 1];
    float4* o4 = (float4*)(out + (size_t)node * NHID + w * 16);
    if (en - st == 0) {
      const float4* hr = (const float4*)(h + (size_t)node * NHID + w * 16);
#pragma unroll
      for (int j4 = 0; j4 < 4; ++j4) o4[j4] = hr[j4];
    } else {
#pragma unroll
      for (int j4 = 0; j4 < 4; ++j4)
        o4[j4] = make_float4(o[j4 * 4 + 0], o[j4 * 4 + 1], o[j4 * 4 + 2],
                             o[j4 * 4 + 3]);
    }
  }
}

extern "C" void kernel_launch(void* const* d_in, const int* in_sizes, int n_in,
                              void* d_out, int out_size, void* d_ws, size_t ws_size,
                              hipStream_t stream) {
  const float* h  = (const float*)d_in[0];
  const float* nf = (const float*)d_in[1];
  const float* ef = (const float*)d_in[2];
  const int*   src = (const int*)d_in[3];
  const int*   dst = (const int*)d_in[4];
  const float* W1 = (const float*)d_in[5];
  const float* W2 = (const float*)d_in[6];
  float* out = (float*)d_out;

  int N = in_sizes[0] / NHID;  // h is [N, 64]
  int E = in_sizes[3];         // src is [E]

  // ws layout (bytes), total ~21.5 MB:
  // sedge[E] int2 | counts[N] | starts[N+1] | bsum[64] | W1T | W2T |
  // pad16 | h16[N*128B] | efsum16[N*32B] | hsum16[N*128B]
  // rank[E] ALIASES hsum16 (hist writes rank; build reads it; gather then
  // overwrites hsum16 — stream-ordered).
  char* p = (char*)d_ws;
  int2* sedge = (int2*)p;                 p += (size_t)E * 8;
  int* counts = (int*)p;                  p += (size_t)N * 4;
  int* starts = (int*)p;                  p += (size_t)(N + 1) * 4;
  int* bsum = (int*)p;                    p += 64 * 4;
  float* W1T = (float*)p;                 p += (size_t)NIN1 * NHID * 4;
  float* W2T = (float*)p;                 p += (size_t)NHID * NHID * 4;
  p = (char*)(((size_t)p + 15) & ~(size_t)15);
  uint4* h16 = (uint4*)p;                 p += (size_t)N * 128;
  uint4* efsum16 = (uint4*)p;             p += (size_t)N * 32;
  uint4* hsum16 = (uint4*)p;              p += (size_t)N * 128;
  int* rank = (int*)hsum16;               // E*4 = 3.2 MB <= N*128 = 6.4 MB

  hipMemsetAsync(counts, 0, (size_t)N * sizeof(int), stream);

  int eblocks8 = (E + 256 * HB - 1) / (256 * HB);  // 391 edge-blocks
  int bblocks  = (E + 256 * BB - 1) / (256 * BB);  // 391 build blocks
  int nb = (N + SCHUNK - 1) / SCHUNK;              // 49 for N=50000

  sse_hist<<<eblocks8 + SBLK, 256, 0, stream>>>(dst, counts, rank, W1, W1T,
                                                W2, W2T, h, h16, E, N,
                                                eblocks8);
  sse_scan_part<<<nb, 256, 0, stream>>>(counts, bsum, N);
  sse_scan_final<<<nb, 256, 0, stream>>>(counts, bsum, starts, N, nb);
  sse_build<<<bblocks, 256, 0, stream>>>(src, dst, rank, starts, sedge, E);

  int gblocks = (N + 3) / 4;  // 1 node/wave, 4 per block
  sse_gather<<<gblocks, 256, 0, stream>>>(h16, ef, sedge, starts,
                                          efsum16, hsum16, N);

  int nblocks = (N + 63) / 64;  // 782 blocks x 4 waves = 3128 waves
  sse_node<<<nblocks, 256, 0, stream>>>(h, nf, efsum16, hsum16, starts, W1T,
                                        W2T, out, N);
}